// Round 1
// baseline (487.584 us; speedup 1.0000x reference)
//
#include <hip/hip_runtime.h>
#include <hip/hip_bf16.h>

// LoRAConv1D: out[8192][4800] = x@W + b + 4.0*(x@A)@B
// Strategy: fold rank-8 LoRA into GEMM K dim (K'=1632), bf16 MFMA.

#define M_ROWS 8192
#define K_DIM  1600
#define N_DIM  4800
#define KP     1632   // 1600 + 8 (lora) + 24 (zero pad) = 51*32

#define BM 128
#define BN 96
#define BK 32
#define LDT 40        // padded LDS row stride (bf16 elems), 80 B (16B-multiple)
#define KT (KP / BK)  // 51

typedef __attribute__((ext_vector_type(4))) float f32x4;
typedef __attribute__((ext_vector_type(8))) short s16x8;

static __device__ __forceinline__ unsigned short f2bf(float f) {
    // round-to-nearest-even fp32 -> bf16 (no NaN concern for this data)
    unsigned int u = __float_as_uint(f);
    u += 0x7fffu + ((u >> 16) & 1u);
    return (unsigned short)(u >> 16);
}

// ---------------------------------------------------------------------------
// prep_x: one block per row m. Phase 1: xa[r] = sum_k x[m][k]*lora_A[k][r].
// Phase 2: write Xbp[m][0..1631] = [bf16(x row) | bf16(xa) | zeros]
// ---------------------------------------------------------------------------
__global__ __launch_bounds__(256) void prep_x(const float* __restrict__ x,
                                              const float* __restrict__ lora_A,
                                              unsigned short* __restrict__ Xbp) {
    const int m = blockIdx.x;
    const int t = threadIdx.x;
    const float* xrow = x + (size_t)m * K_DIM;

    float acc[8];
#pragma unroll
    for (int r = 0; r < 8; ++r) acc[r] = 0.f;

    for (int g = t; g < 400; g += 256) {     // 400 float4 groups = 1600 cols
        float4 xv = ((const float4*)xrow)[g];
        float xs[4] = {xv.x, xv.y, xv.z, xv.w};
#pragma unroll
        for (int i = 0; i < 4; ++i) {
            const float4* la = (const float4*)(lora_A + (size_t)(4 * g + i) * 8);
            float4 l0 = la[0], l1 = la[1];
            acc[0] += xs[i] * l0.x; acc[1] += xs[i] * l0.y;
            acc[2] += xs[i] * l0.z; acc[3] += xs[i] * l0.w;
            acc[4] += xs[i] * l1.x; acc[5] += xs[i] * l1.y;
            acc[6] += xs[i] * l1.z; acc[7] += xs[i] * l1.w;
        }
    }

    __shared__ float redw[4][8];
    __shared__ float xarow[8];
    const int lane = t & 63, wid = t >> 6;
#pragma unroll
    for (int off = 32; off > 0; off >>= 1) {
#pragma unroll
        for (int r = 0; r < 8; ++r) acc[r] += __shfl_down(acc[r], off, 64);
    }
    if (lane == 0) {
#pragma unroll
        for (int r = 0; r < 8; ++r) redw[wid][r] = acc[r];
    }
    __syncthreads();
    if (t < 8) xarow[t] = redw[0][t] + redw[1][t] + redw[2][t] + redw[3][t];
    __syncthreads();

    unsigned short* orow = Xbp + (size_t)m * KP;
    for (int g = t; g < 408; g += 256) {     // 408 ushort4 groups = 1632 cols
        ushort4 o;
        if (g < 400) {
            float4 xv = ((const float4*)xrow)[g];
            o.x = f2bf(xv.x); o.y = f2bf(xv.y); o.z = f2bf(xv.z); o.w = f2bf(xv.w);
        } else if (g < 402) {
            const int b0 = (g - 400) * 4;
            o.x = f2bf(xarow[b0 + 0]); o.y = f2bf(xarow[b0 + 1]);
            o.z = f2bf(xarow[b0 + 2]); o.w = f2bf(xarow[b0 + 3]);
        } else {
            o.x = 0; o.y = 0; o.z = 0; o.w = 0;
        }
        ((ushort4*)orow)[g] = o;
    }
}

// ---------------------------------------------------------------------------
// prep_w: 32x32 LDS transpose, W[1600][4800] fp32 -> Wtp[4800][1632] bf16
// (cols 0..1599 only; lora cols written by prep_lb)
// ---------------------------------------------------------------------------
__global__ __launch_bounds__(256) void prep_w(const float* __restrict__ W,
                                              unsigned short* __restrict__ Wtp) {
    __shared__ float tile[32][33];
    const int n0 = blockIdx.x * 32;
    const int k0 = blockIdx.y * 32;
    const int t  = threadIdx.x;
    const int r  = t >> 3;         // 0..31
    const int c4 = (t & 7) * 4;    // 0..28

    float4 v = *(const float4*)(W + (size_t)(k0 + r) * N_DIM + n0 + c4);
    tile[r][c4 + 0] = v.x; tile[r][c4 + 1] = v.y;
    tile[r][c4 + 2] = v.z; tile[r][c4 + 3] = v.w;
    __syncthreads();

    ushort4 o;
    o.x = f2bf(tile[c4 + 0][r]);
    o.y = f2bf(tile[c4 + 1][r]);
    o.z = f2bf(tile[c4 + 2][r]);
    o.w = f2bf(tile[c4 + 3][r]);
    *(ushort4*)(Wtp + (size_t)(n0 + r) * KP + k0 + c4) = o;
}

// ---------------------------------------------------------------------------
// prep_lb: Wtp[n][1600..1607] = bf16(4.0*lora_B[r][n]); [1608..1631] = 0
// ---------------------------------------------------------------------------
__global__ __launch_bounds__(256) void prep_lb(const float* __restrict__ lora_B,
                                               unsigned short* __restrict__ Wtp) {
    const int n = blockIdx.x * 256 + threadIdx.x;
    if (n >= N_DIM) return;
    unsigned short vals[32];
#pragma unroll
    for (int r = 0; r < 8; ++r) vals[r] = f2bf(4.0f * lora_B[(size_t)r * N_DIM + n]);
#pragma unroll
    for (int i = 8; i < 32; ++i) vals[i] = 0;
    ushort4* d4 = (ushort4*)(Wtp + (size_t)n * KP + 1600);
#pragma unroll
    for (int i = 0; i < 8; ++i) {
        ushort4 o;
        o.x = vals[4 * i + 0]; o.y = vals[4 * i + 1];
        o.z = vals[4 * i + 2]; o.w = vals[4 * i + 3];
        d4[i] = o;
    }
}

// ---------------------------------------------------------------------------
// gemm_bt: C[m][n] = sum_k Ab[m][k]*Bb[n][k] + bias[n]
// Ab: [8192][1632] bf16 (K-contig), Bb: [4800][1632] bf16 (K-contig)
// Block 256 thr = 4 waves (2x2), tile 128x96, wave tile 64x48 (4x3 MFMA tiles)
// ---------------------------------------------------------------------------
__global__ __launch_bounds__(256) void gemm_bt(const unsigned short* __restrict__ Ab,
                                               const unsigned short* __restrict__ Bb,
                                               const float* __restrict__ bias,
                                               float* __restrict__ out) {
    __shared__ unsigned short lsA[BM * LDT];   // 128*40*2 = 10240 B
    __shared__ unsigned short lsB[BN * LDT];   //  96*40*2 =  7680 B

    const int t    = threadIdx.x;
    const int n0   = blockIdx.x * BN;
    const int m0   = blockIdx.y * BM;
    const int lane = t & 63;
    const int w    = t >> 6;
    const int wr   = (w >> 1) * 64;   // wave row origin
    const int wc   = (w & 1) * 48;    // wave col origin
    const int lr   = lane & 15;
    const int quad = lane >> 4;

    // staging: A = 512 16B-groups (2/thread), B = 384 (1.5/thread)
    const int rowS = t >> 2;          // 0..63
    const int kgS  = (t & 3) * 8;
    const unsigned short* srcA0 = Ab + (size_t)(m0 + rowS) * KP + kgS;
    const unsigned short* srcA1 = srcA0 + (size_t)64 * KP;
    const unsigned short* srcB0 = Bb + (size_t)(n0 + rowS) * KP + kgS;
    const unsigned short* srcB1 = srcB0 + (size_t)64 * KP;   // t<128 only
    const int dstA0 = rowS * LDT + kgS;
    const int dstA1 = dstA0 + 64 * LDT;
    const int dstB0 = rowS * LDT + kgS;
    const int dstB1 = dstB0 + 64 * LDT;

    int aoff[4], boff[3];
#pragma unroll
    for (int mt = 0; mt < 4; ++mt) aoff[mt] = (wr + mt * 16 + lr) * LDT + quad * 8;
#pragma unroll
    for (int nt = 0; nt < 3; ++nt) boff[nt] = (wc + nt * 16 + lr) * LDT + quad * 8;

    f32x4 acc[4][3];
#pragma unroll
    for (int mt = 0; mt < 4; ++mt)
#pragma unroll
        for (int nt = 0; nt < 3; ++nt) acc[mt][nt] = (f32x4)0.f;

    for (int kt = 0; kt < KT; ++kt) {
        uint4 a0 = *(const uint4*)srcA0;
        uint4 a1 = *(const uint4*)srcA1;
        uint4 b0 = *(const uint4*)srcB0;
        uint4 b1;
        if (t < 128) b1 = *(const uint4*)srcB1;

        __syncthreads();   // previous iter's fragment reads complete
        *(uint4*)&lsA[dstA0] = a0;
        *(uint4*)&lsA[dstA1] = a1;
        *(uint4*)&lsB[dstB0] = b0;
        if (t < 128) *(uint4*)&lsB[dstB1] = b1;
        __syncthreads();

        s16x8 af[4], bf[3];
#pragma unroll
        for (int mt = 0; mt < 4; ++mt) af[mt] = *(const s16x8*)&lsA[aoff[mt]];
#pragma unroll
        for (int nt = 0; nt < 3; ++nt) bf[nt] = *(const s16x8*)&lsB[boff[nt]];
#pragma unroll
        for (int mt = 0; mt < 4; ++mt)
#pragma unroll
            for (int nt = 0; nt < 3; ++nt)
                acc[mt][nt] = __builtin_amdgcn_mfma_f32_16x16x32_bf16(
                    af[mt], bf[nt], acc[mt][nt], 0, 0, 0);

        srcA0 += BK; srcA1 += BK; srcB0 += BK; srcB1 += BK;
    }

    // epilogue: C/D layout col=lane&15, row=(lane>>4)*4+reg
#pragma unroll
    for (int nt = 0; nt < 3; ++nt) {
        const int gc = n0 + wc + nt * 16 + lr;
        const float bv = bias[gc];
#pragma unroll
        for (int mt = 0; mt < 4; ++mt) {
#pragma unroll
            for (int r = 0; r < 4; ++r) {
                const int grow = m0 + wr + mt * 16 + quad * 4 + r;
                out[(size_t)grow * N_DIM + gc] = acc[mt][nt][r] + bv;
            }
        }
    }
}

// ---------------------------------------------------------------------------
extern "C" void kernel_launch(void* const* d_in, const int* in_sizes, int n_in,
                              void* d_out, int out_size, void* d_ws, size_t ws_size,
                              hipStream_t stream) {
    const float* x      = (const float*)d_in[0];
    const float* W      = (const float*)d_in[1];
    const float* b      = (const float*)d_in[2];
    const float* lora_A = (const float*)d_in[3];
    const float* lora_B = (const float*)d_in[4];
    float* out = (float*)d_out;

    unsigned short* Xbp = (unsigned short*)d_ws;              // 8192*1632 bf16
    unsigned short* Wtp = Xbp + (size_t)M_ROWS * KP;          // 4800*1632 bf16
    // ws bytes needed: (8192+4800)*1632*2 = 42,405,888

    prep_x<<<M_ROWS, 256, 0, stream>>>(x, lora_A, Xbp);
    prep_w<<<dim3(N_DIM / 32, K_DIM / 32), 256, 0, stream>>>(W, Wtp);
    prep_lb<<<(N_DIM + 255) / 256, 256, 0, stream>>>(lora_B, Wtp);
    gemm_bt<<<dim3(N_DIM / BN, M_ROWS / BM), 256, 0, stream>>>(Xbp, Wtp, b, out);
}

// Round 2
// 473.570 us; speedup vs baseline: 1.0296x; 1.0296x over previous
//
#include <hip/hip_runtime.h>
#include <hip/hip_bf16.h>

// LoRAConv1D: out[8192][4800] = x@W + b + 4.0*(x@A)@B
// Fold rank-8 LoRA into GEMM K dim (K'=1632), bf16 MFMA, m97-style
// global_load_lds staging (unpadded LDS, wave-uniform base + lane*16).

#define M_ROWS 8192
#define K_DIM  1600
#define N_DIM  4800
#define KP     1632   // 1600 + 8 (lora) + 24 (zero pad) = 51*32

#define BM 128
#define BN 96
#define BK 32
#define KT (KP / BK)  // 51

typedef __attribute__((ext_vector_type(4))) float f32x4;
typedef __attribute__((ext_vector_type(8))) short s16x8;

static __device__ __forceinline__ unsigned short f2bf(float f) {
    unsigned int u = __float_as_uint(f);
    u += 0x7fffu + ((u >> 16) & 1u);
    return (unsigned short)(u >> 16);
}

typedef __attribute__((address_space(3))) unsigned int as3_uint;
typedef __attribute__((address_space(1))) const unsigned int as1_uint;

static __device__ __forceinline__ void gl16(const unsigned short* g,
                                            unsigned short* l) {
    // 16B per lane, LDS dst = wave-uniform base + lane*16
    __builtin_amdgcn_global_load_lds((as1_uint*)g, (as3_uint*)l, 16, 0, 0);
}

// ---------------------------------------------------------------------------
// prep_x: one WAVE per row m. Single pass over the row: cast-store bf16 AND
// accumulate xa[r] = sum_k x[m][k]*lora_A[k][r]. No LDS, no block barriers.
// ---------------------------------------------------------------------------
__global__ __launch_bounds__(256) void prep_x(const float* __restrict__ x,
                                              const float* __restrict__ lora_A,
                                              unsigned short* __restrict__ Xbp) {
    const int gw   = (blockIdx.x * 256 + threadIdx.x) >> 6;  // global wave = row
    const int lane = threadIdx.x & 63;
    const float* xrow = x + (size_t)gw * K_DIM;
    unsigned short* orow = Xbp + (size_t)gw * KP;

    float acc[8];
#pragma unroll
    for (int r = 0; r < 8; ++r) acc[r] = 0.f;

    for (int g = lane; g < 400; g += 64) {     // 400 float4 groups
        float4 xv = ((const float4*)xrow)[g];
        ushort4 o;
        o.x = f2bf(xv.x); o.y = f2bf(xv.y); o.z = f2bf(xv.z); o.w = f2bf(xv.w);
        ((ushort4*)orow)[g] = o;
        float xs[4] = {xv.x, xv.y, xv.z, xv.w};
#pragma unroll
        for (int i = 0; i < 4; ++i) {
            const float4* la = (const float4*)(lora_A + (size_t)(4 * g + i) * 8);
            float4 l0 = la[0], l1 = la[1];
            acc[0] += xs[i] * l0.x; acc[1] += xs[i] * l0.y;
            acc[2] += xs[i] * l0.z; acc[3] += xs[i] * l0.w;
            acc[4] += xs[i] * l1.x; acc[5] += xs[i] * l1.y;
            acc[6] += xs[i] * l1.z; acc[7] += xs[i] * l1.w;
        }
    }

#pragma unroll
    for (int off = 32; off > 0; off >>= 1)
#pragma unroll
        for (int r = 0; r < 8; ++r) acc[r] += __shfl_down(acc[r], off, 64);

    float xa[8];
#pragma unroll
    for (int r = 0; r < 8; ++r) xa[r] = __shfl(acc[r], 0, 64);

    if (lane < 8) {   // tail groups 400..407: [xa | zeros]
        ushort4 o;
        if (lane == 0)      { o.x = f2bf(xa[0]); o.y = f2bf(xa[1]); o.z = f2bf(xa[2]); o.w = f2bf(xa[3]); }
        else if (lane == 1) { o.x = f2bf(xa[4]); o.y = f2bf(xa[5]); o.z = f2bf(xa[6]); o.w = f2bf(xa[7]); }
        else                { o.x = 0; o.y = 0; o.z = 0; o.w = 0; }
        ((ushort4*)orow)[400 + lane] = o;
    }
}

// ---------------------------------------------------------------------------
// prep_w: 64n x 32k tile transpose. W[1600][4800] fp32 -> Wtp[4800][1632] bf16
// 16B packed stores on the write side.
// ---------------------------------------------------------------------------
__global__ __launch_bounds__(256) void prep_w(const float* __restrict__ W,
                                              unsigned short* __restrict__ Wtp) {
    __shared__ float tile[32][65];
    const int n0 = blockIdx.x * 64;
    const int k0 = blockIdx.y * 32;
    const int t  = threadIdx.x;

#pragma unroll
    for (int p = 0; p < 2; ++p) {
        const int k  = p * 16 + (t >> 4);
        const int c4 = (t & 15) * 4;
        float4 v = *(const float4*)(W + (size_t)(k0 + k) * N_DIM + n0 + c4);
        tile[k][c4 + 0] = v.x; tile[k][c4 + 1] = v.y;
        tile[k][c4 + 2] = v.z; tile[k][c4 + 3] = v.w;
    }
    __syncthreads();

    const int n   = t >> 2;        // 0..63
    const int seg = t & 3;         // 8 k-elems each
    unsigned int pk[4];
#pragma unroll
    for (int h = 0; h < 4; ++h) {
        unsigned int lo = f2bf(tile[seg * 8 + 2 * h + 0][n]);
        unsigned int hi = f2bf(tile[seg * 8 + 2 * h + 1][n]);
        pk[h] = lo | (hi << 16);
    }
    uint4 o = {pk[0], pk[1], pk[2], pk[3]};
    *(uint4*)(Wtp + (size_t)(n0 + n) * KP + k0 + seg * 8) = o;
}

// ---------------------------------------------------------------------------
// prep_lb: Wtp[n][1600..1607] = bf16(4.0*lora_B[r][n]); [1608..1631] = 0
// ---------------------------------------------------------------------------
__global__ __launch_bounds__(256) void prep_lb(const float* __restrict__ lora_B,
                                               unsigned short* __restrict__ Wtp) {
    const int n = blockIdx.x * 256 + threadIdx.x;
    if (n >= N_DIM) return;
    unsigned short vals[32];
#pragma unroll
    for (int r = 0; r < 8; ++r) vals[r] = f2bf(4.0f * lora_B[(size_t)r * N_DIM + n]);
#pragma unroll
    for (int i = 8; i < 32; ++i) vals[i] = 0;
    ushort4* d4 = (ushort4*)(Wtp + (size_t)n * KP + 1600);
#pragma unroll
    for (int i = 0; i < 8; ++i) {
        ushort4 o;
        o.x = vals[4 * i + 0]; o.y = vals[4 * i + 1];
        o.z = vals[4 * i + 2]; o.w = vals[4 * i + 3];
        d4[i] = o;
    }
}

// ---------------------------------------------------------------------------
// gemm_bt: C[m][n] = sum_k Ab[m][k]*Bb[n][k] + bias[n]
// m97 structure: global_load_lds width-16 staging into unpadded [rows][32]
// LDS, 2-barrier K-loop. Block 256 = 4 waves (2x2), wave tile 64x48.
// ---------------------------------------------------------------------------
__global__ __launch_bounds__(256) void gemm_bt(const unsigned short* __restrict__ Ab,
                                               const unsigned short* __restrict__ Bb,
                                               const float* __restrict__ bias,
                                               float* __restrict__ out) {
    __shared__ unsigned short lsA[BM * BK];   // 8192 B, unpadded [128][32]
    __shared__ unsigned short lsB[BN * BK];   // 6144 B, unpadded [96][32]

    const int t    = threadIdx.x;
    const int n0   = blockIdx.x * BN;
    const int m0   = blockIdx.y * BM;
    const int lane = t & 63;
    const int w    = t >> 6;
    const int wr   = (w >> 1) * 64;
    const int wc   = (w & 1) * 48;
    const int lr   = lane & 15;
    const int quad = lane >> 4;

    // staging source pattern: chunk = 16 rows x 32 k = 1 KB = 64 lanes x 16B
    // lane i -> row i>>2, k-group (i&3)*8  (matches LDS base + lane*16)
    const int rS = lane >> 2;
    const int kS = (lane & 3) * 8;
    const unsigned short* srcA = Ab + (size_t)(m0 + rS) * KP + kS;
    const unsigned short* srcB = Bb + (size_t)(n0 + rS) * KP + kS;

    int aoff[4], boff[3];
#pragma unroll
    for (int mt = 0; mt < 4; ++mt) aoff[mt] = (wr + mt * 16 + lr) * BK + quad * 8;
#pragma unroll
    for (int nt = 0; nt < 3; ++nt) boff[nt] = (wc + nt * 16 + lr) * BK + quad * 8;

    f32x4 acc[4][3];
#pragma unroll
    for (int mt = 0; mt < 4; ++mt)
#pragma unroll
        for (int nt = 0; nt < 3; ++nt) acc[mt][nt] = (f32x4)0.f;

    for (int kt = 0; kt < KT; ++kt) {
        const int kb = kt * BK;
        __syncthreads();   // previous iter's fragment reads complete
        // A: 8 chunks of 16 rows; B: 6 chunks — round-robin across waves
#pragma unroll
        for (int c = w; c < 8; c += 4)
            gl16(srcA + (size_t)c * 16 * KP + kb, &lsA[c * 512]);
#pragma unroll
        for (int c = w; c < 6; c += 4)
            gl16(srcB + (size_t)c * 16 * KP + kb, &lsB[c * 512]);
        __syncthreads();   // vmcnt(0) drained before barrier: staging visible

        s16x8 af[4], bf[3];
#pragma unroll
        for (int mt = 0; mt < 4; ++mt) af[mt] = *(const s16x8*)&lsA[aoff[mt]];
#pragma unroll
        for (int nt = 0; nt < 3; ++nt) bf[nt] = *(const s16x8*)&lsB[boff[nt]];
#pragma unroll
        for (int mt = 0; mt < 4; ++mt)
#pragma unroll
            for (int nt = 0; nt < 3; ++nt)
                acc[mt][nt] = __builtin_amdgcn_mfma_f32_16x16x32_bf16(
                    af[mt], bf[nt], acc[mt][nt], 0, 0, 0);
    }

    // epilogue: C/D layout col=lane&15, row=(lane>>4)*4+reg
#pragma unroll
    for (int nt = 0; nt < 3; ++nt) {
        const int gc = n0 + wc + nt * 16 + lr;
        const float bv = bias[gc];
#pragma unroll
        for (int mt = 0; mt < 4; ++mt) {
#pragma unroll
            for (int r = 0; r < 4; ++r) {
                const int grow = m0 + wr + mt * 16 + quad * 4 + r;
                out[(size_t)grow * N_DIM + gc] = acc[mt][nt][r] + bv;
            }
        }
    }
}

// ---------------------------------------------------------------------------
extern "C" void kernel_launch(void* const* d_in, const int* in_sizes, int n_in,
                              void* d_out, int out_size, void* d_ws, size_t ws_size,
                              hipStream_t stream) {
    const float* x      = (const float*)d_in[0];
    const float* W      = (const float*)d_in[1];
    const float* b      = (const float*)d_in[2];
    const float* lora_A = (const float*)d_in[3];
    const float* lora_B = (const float*)d_in[4];
    float* out = (float*)d_out;

    unsigned short* Xbp = (unsigned short*)d_ws;              // 8192*1632 bf16
    unsigned short* Wtp = Xbp + (size_t)M_ROWS * KP;          // 4800*1632 bf16
    // ws bytes: (8192+4800)*1632*2 = 42,405,888

    prep_x<<<M_ROWS / 4, 256, 0, stream>>>(x, lora_A, Xbp);   // 1 wave/row
    prep_w<<<dim3(N_DIM / 64, K_DIM / 32), 256, 0, stream>>>(W, Wtp);
    prep_lb<<<(N_DIM + 255) / 256, 256, 0, stream>>>(lora_B, Wtp);
    gemm_bt<<<dim3(N_DIM / BN, M_ROWS / BM), 256, 0, stream>>>(Xbp, Wtp, b, out);
}

// Round 3
// 390.377 us; speedup vs baseline: 1.2490x; 1.2131x over previous
//
#include <hip/hip_runtime.h>
#include <hip/hip_bf16.h>

// LoRAConv1D: out[8192][4800] = x@W + b + 4.0*(x@A)@B
// Rank-8 LoRA folded into GEMM K dim (K'=1664=26*64), bf16 MFMA.
// gemm: BM=128 BN=160 BK=64, global_load_lds w/ XOR-swizzled source so
// fragment ds_read_b128 are conflict-free on the 128B row stride.

#define M_ROWS 8192
#define K_DIM  1600
#define N_DIM  4800
#define KP     1664   // 1600 + 8 (lora) + 56 zero pad = 26*64

#define BM 128
#define BN 160
#define BK 64
#define KT (KP / BK)  // 26

typedef __attribute__((ext_vector_type(4))) float f32x4;
typedef __attribute__((ext_vector_type(8))) short s16x8;

static __device__ __forceinline__ unsigned short f2bf(float f) {
    unsigned int u = __float_as_uint(f);
    u += 0x7fffu + ((u >> 16) & 1u);
    return (unsigned short)(u >> 16);
}

typedef __attribute__((address_space(3))) unsigned int as3_uint;
typedef __attribute__((address_space(1))) const unsigned int as1_uint;

static __device__ __forceinline__ void gl16(const unsigned short* g,
                                            unsigned short* l) {
    __builtin_amdgcn_global_load_lds((as1_uint*)g, (as3_uint*)l, 16, 0, 0);
}

// ---------------------------------------------------------------------------
// prep_x: 16 rows per block, lora_A staged in LDS (51.2 KB) once per block.
// Each wave processes 4 rows: stream x (cast-store bf16) + rank-8 dot accum.
// ---------------------------------------------------------------------------
__global__ __launch_bounds__(256) void prep_x(const float* __restrict__ x,
                                              const float* __restrict__ lora_A,
                                              unsigned short* __restrict__ Xbp) {
    __shared__ float4 lA4[3200];   // lora_A [1600][8] as float4 pairs
    const int t = threadIdx.x;
    for (int g = t; g < 3200; g += 256) lA4[g] = ((const float4*)lora_A)[g];
    __syncthreads();

    const int lane = t & 63;
    const int w    = t >> 6;

    for (int i = 0; i < 4; ++i) {
        const int m = blockIdx.x * 16 + w * 4 + i;
        const float* xrow = x + (size_t)m * K_DIM;
        unsigned short* orow = Xbp + (size_t)m * KP;

        float acc[8];
#pragma unroll
        for (int r = 0; r < 8; ++r) acc[r] = 0.f;

        for (int g = lane; g < 400; g += 64) {
            float4 xv = ((const float4*)xrow)[g];
            ushort4 o;
            o.x = f2bf(xv.x); o.y = f2bf(xv.y); o.z = f2bf(xv.z); o.w = f2bf(xv.w);
            ((ushort4*)orow)[g] = o;
            float xs[4] = {xv.x, xv.y, xv.z, xv.w};
#pragma unroll
            for (int j = 0; j < 4; ++j) {
                float4 l0 = lA4[(4 * g + j) * 2 + 0];
                float4 l1 = lA4[(4 * g + j) * 2 + 1];
                acc[0] += xs[j] * l0.x; acc[1] += xs[j] * l0.y;
                acc[2] += xs[j] * l0.z; acc[3] += xs[j] * l0.w;
                acc[4] += xs[j] * l1.x; acc[5] += xs[j] * l1.y;
                acc[6] += xs[j] * l1.z; acc[7] += xs[j] * l1.w;
            }
        }

#pragma unroll
        for (int off = 32; off > 0; off >>= 1)
#pragma unroll
            for (int r = 0; r < 8; ++r) acc[r] += __shfl_down(acc[r], off, 64);

        float xa[8];
#pragma unroll
        for (int r = 0; r < 8; ++r) xa[r] = __shfl(acc[r], 0, 64);

        if (lane < 16) {   // tail groups 400..415: [xa | zeros]
            ushort4 o;
            if (lane == 0)      { o.x = f2bf(xa[0]); o.y = f2bf(xa[1]); o.z = f2bf(xa[2]); o.w = f2bf(xa[3]); }
            else if (lane == 1) { o.x = f2bf(xa[4]); o.y = f2bf(xa[5]); o.z = f2bf(xa[6]); o.w = f2bf(xa[7]); }
            else                { o.x = 0; o.y = 0; o.z = 0; o.w = 0; }
            ((ushort4*)orow)[400 + lane] = o;
        }
    }
}

// ---------------------------------------------------------------------------
// prep_w: 64n x 32k tile transpose, W[1600][4800] fp32 -> Wtp[4800][KP] bf16
// ---------------------------------------------------------------------------
__global__ __launch_bounds__(256) void prep_w(const float* __restrict__ W,
                                              unsigned short* __restrict__ Wtp) {
    __shared__ float tile[32][65];
    const int n0 = blockIdx.x * 64;
    const int k0 = blockIdx.y * 32;
    const int t  = threadIdx.x;

#pragma unroll
    for (int p = 0; p < 2; ++p) {
        const int k  = p * 16 + (t >> 4);
        const int c4 = (t & 15) * 4;
        float4 v = *(const float4*)(W + (size_t)(k0 + k) * N_DIM + n0 + c4);
        tile[k][c4 + 0] = v.x; tile[k][c4 + 1] = v.y;
        tile[k][c4 + 2] = v.z; tile[k][c4 + 3] = v.w;
    }
    __syncthreads();

    const int n   = t >> 2;
    const int seg = t & 3;
    unsigned int pk[4];
#pragma unroll
    for (int h = 0; h < 4; ++h) {
        unsigned int lo = f2bf(tile[seg * 8 + 2 * h + 0][n]);
        unsigned int hi = f2bf(tile[seg * 8 + 2 * h + 1][n]);
        pk[h] = lo | (hi << 16);
    }
    uint4 o = {pk[0], pk[1], pk[2], pk[3]};
    *(uint4*)(Wtp + (size_t)(n0 + n) * KP + k0 + seg * 8) = o;
}

// ---------------------------------------------------------------------------
// prep_lb: Wtp[n][1600..1607] = bf16(4*lora_B[r][n]); [1608..1663] = 0
// ---------------------------------------------------------------------------
__global__ __launch_bounds__(256) void prep_lb(const float* __restrict__ lora_B,
                                               unsigned short* __restrict__ Wtp) {
    const int n = blockIdx.x * 256 + threadIdx.x;
    if (n >= N_DIM) return;
    ushort4* d4 = (ushort4*)(Wtp + (size_t)n * KP + 1600);
    ushort4 o0, o1, z;
    o0.x = f2bf(4.0f * lora_B[0 * N_DIM + n]);
    o0.y = f2bf(4.0f * lora_B[1 * N_DIM + n]);
    o0.z = f2bf(4.0f * lora_B[2 * N_DIM + n]);
    o0.w = f2bf(4.0f * lora_B[3 * N_DIM + n]);
    o1.x = f2bf(4.0f * lora_B[4 * N_DIM + n]);
    o1.y = f2bf(4.0f * lora_B[5 * N_DIM + n]);
    o1.z = f2bf(4.0f * lora_B[6 * N_DIM + n]);
    o1.w = f2bf(4.0f * lora_B[7 * N_DIM + n]);
    z.x = 0; z.y = 0; z.z = 0; z.w = 0;
    d4[0] = o0;
    d4[1] = o1;
#pragma unroll
    for (int i = 2; i < 16; ++i) d4[i] = z;
}

// ---------------------------------------------------------------------------
// gemm_bt: C[m][n] = sum_k Ab[m][k]*Bb[n][k] + bias[n]
// LDS layout (swizzled): row r, kgroup g (8 elems) stored at
//   elem offset r*64 + (g ^ (r&7))*8.
// Staging chunk = 8 rows x 64 k = 1 KB = one gl16; source kgroup for dst
// slot `lane` is (lane&7)^((lane>>3)&7), so the swizzle is applied on the
// SOURCE address while LDS dst stays base+lane*16 (HW requirement).
// Fragment ds_read_b128: banks 4*(g^(lr&7)) -> 2-way only (free).
// 4 waves (2x2), wave tile 64x80 = 4x5 MFMA tiles, 40 MFMA/wave/barrier.
// ---------------------------------------------------------------------------
__global__ __launch_bounds__(256, 3) void gemm_bt(const unsigned short* __restrict__ Ab,
                                                  const unsigned short* __restrict__ Bb,
                                                  const float* __restrict__ bias,
                                                  float* __restrict__ out) {
    __shared__ unsigned short lsA[BM * BK];   // 16 KB
    __shared__ unsigned short lsB[BN * BK];   // 20 KB

    const int t    = threadIdx.x;
    const int n0   = blockIdx.x * BN;
    const int m0   = blockIdx.y * BM;
    const int lane = t & 63;
    const int w    = t >> 6;
    const int wr   = (w >> 1) * 64;
    const int wc   = (w & 1) * 80;
    const int lr   = lane & 15;
    const int quad = lane >> 4;

    // staging source addressing (swizzled kgroup)
    const int rS = lane >> 3;                        // 0..7 within chunk
    const int gS = ((lane & 7) ^ (rS & 7)) * 8;      // source k offset
    const unsigned short* srcA = Ab + (size_t)(m0 + rS) * KP + gS;
    const unsigned short* srcB = Bb + (size_t)(n0 + rS) * KP + gS;

    int rowA[4], rowB[5];
#pragma unroll
    for (int mt = 0; mt < 4; ++mt) rowA[mt] = (wr + mt * 16 + lr) * BK;
#pragma unroll
    for (int nt = 0; nt < 5; ++nt) rowB[nt] = (wc + nt * 16 + lr) * BK;
    const int lx = lr & 7;

    f32x4 acc[4][5];
#pragma unroll
    for (int mt = 0; mt < 4; ++mt)
#pragma unroll
        for (int nt = 0; nt < 5; ++nt) acc[mt][nt] = (f32x4)0.f;

    for (int kt = 0; kt < KT; ++kt) {
        const int kb = kt * BK;
        __syncthreads();   // previous iter's fragment reads complete
        // A: 16 chunks of 8 rows; B: 20 chunks — round-robin across waves
#pragma unroll
        for (int c = w; c < 16; c += 4)
            gl16(srcA + (size_t)c * 8 * KP + kb, &lsA[c * 512]);
#pragma unroll
        for (int c = w; c < 20; c += 4)
            gl16(srcB + (size_t)c * 8 * KP + kb, &lsB[c * 512]);
        __syncthreads();   // staging visible

#pragma unroll
        for (int ksub = 0; ksub < 2; ++ksub) {
            const int g0 = quad + ksub * 4;
            const int koff = ((g0 ^ lx)) * 8;
            s16x8 af[4], bf[5];
#pragma unroll
            for (int mt = 0; mt < 4; ++mt) af[mt] = *(const s16x8*)&lsA[rowA[mt] + koff];
#pragma unroll
            for (int nt = 0; nt < 5; ++nt) bf[nt] = *(const s16x8*)&lsB[rowB[nt] + koff];
#pragma unroll
            for (int mt = 0; mt < 4; ++mt)
#pragma unroll
                for (int nt = 0; nt < 5; ++nt)
                    acc[mt][nt] = __builtin_amdgcn_mfma_f32_16x16x32_bf16(
                        af[mt], bf[nt], acc[mt][nt], 0, 0, 0);
        }
    }

    // epilogue: C/D layout col=lane&15, row=(lane>>4)*4+reg
#pragma unroll
    for (int nt = 0; nt < 5; ++nt) {
        const int gc = n0 + wc + nt * 16 + lr;
        const float bv = bias[gc];
#pragma unroll
        for (int mt = 0; mt < 4; ++mt) {
#pragma unroll
            for (int r = 0; r < 4; ++r) {
                const int grow = m0 + wr + mt * 16 + quad * 4 + r;
                out[(size_t)grow * N_DIM + gc] = acc[mt][nt][r] + bv;
            }
        }
    }
}

// ---------------------------------------------------------------------------
extern "C" void kernel_launch(void* const* d_in, const int* in_sizes, int n_in,
                              void* d_out, int out_size, void* d_ws, size_t ws_size,
                              hipStream_t stream) {
    const float* x      = (const float*)d_in[0];
    const float* W      = (const float*)d_in[1];
    const float* b      = (const float*)d_in[2];
    const float* lora_A = (const float*)d_in[3];
    const float* lora_B = (const float*)d_in[4];
    float* out = (float*)d_out;

    unsigned short* Xbp = (unsigned short*)d_ws;              // 8192*1664 bf16
    unsigned short* Wtp = Xbp + (size_t)M_ROWS * KP;          // 4800*1664 bf16
    // ws bytes: (8192+4800)*1664*2 = 43,225,088

    prep_x<<<M_ROWS / 16, 256, 0, stream>>>(x, lora_A, Xbp);
    prep_w<<<dim3(N_DIM / 64, K_DIM / 32), 256, 0, stream>>>(W, Wtp);
    prep_lb<<<(N_DIM + 255) / 256, 256, 0, stream>>>(lora_B, Wtp);
    gemm_bt<<<dim3(N_DIM / BN, M_ROWS / BM), 256, 0, stream>>>(Xbp, Wtp, b, out);
}